// Round 4
// baseline (76.977 us; speedup 1.0000x reference)
//
#include <hip/hip_runtime.h>
#include <math.h>

#define DIM 16

typedef __attribute__((ext_vector_type(8))) _Float16 half8;
typedef __attribute__((ext_vector_type(16))) float f32x16;

// ---------------------------------------------------------------------------
// Fused kernel. Per block (256 threads, 512 patches):
//   Phase 0: lanes tid<36 write sincos(params/2) to LDS.         [barrier]
//   Phase 1: lanes tid<16 evolve basis column `tid` of the 16x16 circuit
//            unitary in registers (fully unrolled), write A-matrix layout to
//            LDS: sA[m][k], m<16: Re U[m][k], m>=16: Im U[m-16][k]. [barrier]
//   Phase 2: all threads: A-fragment from LDS once (hi/lo f16 split ->
//            ~fp32 precision), then 4 iterations x 32 patches/wave:
//              B[k][n] = psi0[k][patch n] (plain f16), 2 MFMAs 32x32x16,
//              in-register probs + signed ZS sums (3-level WHT with
//              compile-time signs), 4x shfl_xor(32) to join k-halves,
//              float4 store.
// No global U round-trip, single launch.
// ---------------------------------------------------------------------------
__global__ __launch_bounds__(256) void quanv_fused_kernel(
    const float* __restrict__ x, const float* __restrict__ params,
    float* __restrict__ out, int npatch) {
  __shared__ float s_c[36], s_s[36];
  __shared__ __align__(16) float sA[512];  // A[m][k] fp32 [32][16]

  const int tid  = threadIdx.x;
  const int lane = tid & 63;
  const int wave = tid >> 6;
  const int nl   = lane & 31;   // A-row m (U row) / C-col (patch in batch)
  const int h    = lane >> 5;   // k-half

  // ---- phase 0: gate-angle sincos ----
  if (tid < 36) {
    float s, c;
    __sincosf(params[tid] * 0.5f, &s, &c);
    s_c[tid] = c; s_s[tid] = s;
  }
  __syncthreads();

  // ---- phase 1: build U (16 lanes of wave 0) ----
  if (tid < DIM) {
    const int col = tid;
    float vr[DIM], vi[DIM];
#pragma unroll
    for (int k = 0; k < DIM; ++k) { vr[k] = (k == col) ? 1.0f : 0.0f; vi[k] = 0.0f; }

    int off = 0;
#pragma unroll
    for (int layer = 0; layer < 3; ++layer) {
#pragma unroll
      for (int w = 0; w < 4; ++w) {
        const int m = 1 << (3 - w);  // wire w <-> bit (3-w), big-endian
        {  // RY
          const float cy = s_c[off], sy = s_s[off]; ++off;
#pragma unroll
          for (int k0 = 0; k0 < DIM; ++k0) {
            if (k0 & m) continue;
            const int k1 = k0 | m;
            const float ar = vr[k0], ai = vi[k0], br = vr[k1], bi = vi[k1];
            vr[k0] = cy * ar - sy * br;  vi[k0] = cy * ai - sy * bi;
            vr[k1] = sy * ar + cy * br;  vi[k1] = sy * ai + cy * bi;
          }
        }
        {  // RZ: diag(e^{-it/2}, e^{+it/2})
          const float cz = s_c[off], sz = s_s[off]; ++off;
#pragma unroll
          for (int k = 0; k < DIM; ++k) {
            const float sg = (k & m) ? sz : -sz;
            const float ar = vr[k], ai = vi[k];
            vr[k] = cz * ar - sg * ai;
            vi[k] = cz * ai + sg * ar;
          }
        }
        {  // RY
          const float cy = s_c[off], sy = s_s[off]; ++off;
#pragma unroll
          for (int k0 = 0; k0 < DIM; ++k0) {
            if (k0 & m) continue;
            const int k1 = k0 | m;
            const float ar = vr[k0], ai = vi[k0], br = vr[k1], bi = vi[k1];
            vr[k0] = cy * ar - sy * br;  vi[k0] = cy * ai - sy * bi;
            vr[k1] = sy * ar + cy * br;  vi[k1] = sy * ai + cy * bi;
          }
        }
      }
      // entangler: CNOT(0,1),(1,2),(2,3),(3,0) as left-mults (row swaps)
#pragma unroll
      for (int g = 0; g < 4; ++g) {
        const int a = (g < 3) ? g : 3;
        const int b = (g < 3) ? (g + 1) : 0;
        const int ca = 1 << (3 - a);
        const int tb = 1 << (3 - b);
#pragma unroll
        for (int r = 0; r < DIM; ++r) {
          if ((r & ca) && !(r & tb)) {
            const int r2 = r | tb;
            float tmp;
            tmp = vr[r]; vr[r] = vr[r2]; vr[r2] = tmp;
            tmp = vi[r]; vi[r] = vi[r2]; vi[r2] = tmp;
          }
        }
      }
    }
#pragma unroll
    for (int n = 0; n < DIM; ++n) {
      sA[n * 16 + col]        = vr[n];
      sA[(16 + n) * 16 + col] = vi[n];
    }
  }
  __syncthreads();

  // ---- phase 2: A-fragment once, then 4 x 32-patch MFMA iterations ----
  const float4* Arow = (const float4*)(sA + nl * 16 + 8 * h);
  const float4 ua = Arow[0];
  const float4 ub = Arow[1];
  const float uf[8] = {ua.x, ua.y, ua.z, ua.w, ub.x, ub.y, ub.z, ub.w};
  half8 Uh, Ul;
#pragma unroll
  for (int j = 0; j < 8; ++j) {
    const _Float16 vh = (_Float16)uf[j];
    Uh[j] = vh;
    Ul[j] = (_Float16)(uf[j] - (float)vh);
  }

  const int base = blockIdx.x * 512 + wave * 128;

#pragma unroll
  for (int it = 0; it < 4; ++it) {
    int n = base + it * 32 + nl;       // patch id (lanes l, l+32: same patch)
    if (n >= npatch) n = npatch - 1;   // safety clamp (grid divides exactly)
    const unsigned nu = (unsigned)n;
    const unsigned b  = nu / 196u;
    const unsigned p  = nu - b * 196u;
    const unsigned r1 = p / 14u;
    const unsigned c1 = p - r1 * 14u;
    const float* xb = x + b * 784u + r1 * 56u + c1 * 2u;
    const float2 t0 = *(const float2*)(xb);       // (0,0),(0,1)
    const float2 t1 = *(const float2*)(xb + 28);  // (1,0),(1,1)

    const float HPI = 1.57079632679489662f;  // theta/2 = px*pi/2
    float c0, s0, c1q, s1q, c2q, s2q, c3q, s3q;
    __sincosf(t0.x * HPI, &s0,  &c0);
    __sincosf(t0.y * HPI, &s1q, &c1q);
    __sincosf(t1.x * HPI, &s2q, &c2q);
    __sincosf(t1.y * HPI, &s3q, &c3q);

    // B-frag: b[j] = psi0[k=8h+j] of own patch; bit3(k)=h -> (h? s0 : c0)
    const float f   = h ? s0 : c0;
    const float ab0 = f * c1q, ab1 = f * s1q;
    const float cd[4] = {c2q * c3q, c2q * s3q, s2q * c3q, s2q * s3q};
    half8 bfrag;
#pragma unroll
    for (int j = 0; j < 8; ++j)
      bfrag[j] = (_Float16)(((j & 4) ? ab1 : ab0) * cd[j & 3]);

    f32x16 C;
#pragma unroll
    for (int r = 0; r < 16; ++r) C[r] = 0.0f;
    C = __builtin_amdgcn_mfma_f32_32x32x16_f16(Uh, bfrag, C, 0, 0, 0);
    C = __builtin_amdgcn_mfma_f32_32x32x16_f16(Ul, bfrag, C, 0, 0, 0);

    // probs: reg r=0..7 -> j = (r&3) + 4h + 8*(r>>2); re=C[r], im=C[r+8]
    float pq[8];
#pragma unroll
    for (int r = 0; r < 8; ++r) pq[r] = fmaf(C[r], C[r], C[r + 8] * C[r + 8]);

    // signed sums: j bits: bit3=(r>>2), bit2=h, bit1=(r>>1)&1, bit0=r&1
    const float s03 = pq[0] + pq[3], s12 = pq[1] + pq[2];
    const float s47 = pq[4] + pq[7], s56 = pq[5] + pq[6];
    float e0 = (s03 + s12) - (s47 + s56);                          // bit3
    float e1 = (s03 + s12) + (s47 + s56);  e1 = h ? -e1 : e1;      // bit2 = h
    float e2 = ((pq[0] + pq[1]) - (pq[2] + pq[3]))
             + ((pq[4] + pq[5]) - (pq[6] + pq[7]));                // bit1
    float e3 = ((pq[0] - pq[1]) + (pq[2] - pq[3]))
             + ((pq[4] - pq[5]) + (pq[6] - pq[7]));                // bit0
    // combine the two k-halves (lane l <-> l^32)
    e0 += __shfl_xor(e0, 32, 64);
    e1 += __shfl_xor(e1, 32, 64);
    e2 += __shfl_xor(e2, 32, 64);
    e3 += __shfl_xor(e3, 32, 64);

    if (h == 0 && n < npatch)
      ((float4*)out)[n] = make_float4(e0, e1, e2, e3);
  }
}

// ---------------------------------------------------------------------------
extern "C" void kernel_launch(void* const* d_in, const int* in_sizes, int n_in,
                              void* d_out, int out_size, void* d_ws, size_t ws_size,
                              hipStream_t stream) {
  const float* x      = (const float*)d_in[0];   // [4096, 784] fp32
  const float* params = (const float*)d_in[1];   // [36] fp32
  float* out = (float*)d_out;                    // [4096, 784] fp32
  (void)d_ws; (void)ws_size;

  const int npatch = in_sizes[0] / 4;            // 4096*196 = 802816
  const int nblk = (npatch + 511) / 512;         // 1568
  quanv_fused_kernel<<<nblk, 256, 0, stream>>>(x, params, out, npatch);
}